// Round 4
// baseline (1676.079 us; speedup 1.0000x reference)
//
#include <hip/hip_runtime.h>
#include <math.h>

#define S_ 1024
#define B_ 128
#define F_ 202
#define H_ 100
#define K_ 19
#define XROW_ 208   // 202 + zero pad, 16B-aligned rows
#define HP_ 128     // h padded: recur reads 2x56, logit reads 8x16

// ---------------------------------------------------------------------------
// Kernel 1: one workgroup per (direction, batch) chain.
//  - x rows reg-staged by wave 3 as float2 (8B-aligned always), issued 2
//    iterations ahead; compiler inserts exact counted vmcnt before ds_write.
//  - raw s_barrier bracketed by memory-clobber asm on BOTH sides (round-2
//    race fix): no memory op can cross the barrier in either direction, and
//    vmem (staging loads / logit atomics) stays in flight across it.
//  - Whh lives in LDS as float2-packed transpose whh2[jj][i] = {W[i][2jj],
//    W[i][2jj+1]}: 28 conflict-free ds_read_b64 per thread (word stride 2 ->
//    2 lanes/bank = free), accumulation bitwise-identical to round-1 tree.
//  - logits: atomicAdd into one Lbuf (round-1-proven; exactly 2 commutative
//    fp32 adds onto 0.0 per cell -> bitwise deterministic; ws fits 10 MB).
// ---------------------------------------------------------------------------
__global__ __launch_bounds__(256, 1) void rnn_chain_kernel(
    const float* __restrict__ x,
    const float* __restrict__ Wih_f, const float* __restrict__ Whh_f,
    const float* __restrict__ bih_f, const float* __restrict__ bhh_f,
    const float* __restrict__ Wih_b, const float* __restrict__ Whh_b,
    const float* __restrict__ bih_b, const float* __restrict__ bhh_b,
    const float* __restrict__ Wout,
    float* __restrict__ Lbuf)
{
    const int tid = threadIdx.x;
    const int dir = blockIdx.x >> 7;   // 0 = forward, 1 = backward
    const int b   = blockIdx.x & 127;

    const float* Wih = dir ? Wih_b : Wih_f;
    const float* Whh = dir ? Whh_b : Whh_f;
    const float* bih = dir ? bih_b : bih_f;
    const float* bhh = dir ? bhh_b : bhh_f;

    __shared__ __align__(16) float  x_buf[4][XROW_];
    __shared__ __align__(16) float  h_buf[2][HP_];
    __shared__ __align__(16) float2 whh2_s[56 * H_];  // [jj][i], jj = j/2

    const int i  = tid >> 1;   // output index (tid < 200)
    const int hf = tid & 1;    // which half of the dot product
    const int lk = tid >> 3;   // logit tag (tid < 152 = 19*8)
    const int ls = tid & 7;

    float wih[104];   // proj slice  (pair splits padded-208 f-range)
    float wlog[16];   // logit slice (8 threads per k split padded-128 j-range)
    float bias = 0.f;

    if (tid < 200) {
        const int f0 = hf * 104;
        #pragma unroll
        for (int q = 0; q < 104; ++q) {
            const int f = f0 + q;
            wih[q] = (f < F_) ? Wih[(size_t)i * F_ + f] : 0.f;
        }
        if (hf == 0) bias = bih[i] + bhh[i];
    }
    if (tid < 152) {
        #pragma unroll
        for (int q = 0; q < 16; ++q) {
            const int j = ls * 16 + q;
            wlog[q] = (j < H_) ? Wout[(size_t)lk * (2 * H_) + dir * H_ + j] : 0.f;
        }
    }

    // Whh -> LDS as packed transpose: whh2_s[jj*100 + i] = {W[i][2jj], W[i][2jj+1]}
    for (int idx = tid; idx < 56 * H_; idx += 256) {
        const int jj = idx / H_, ii = idx - jj * H_;
        const int j0 = 2 * jj;
        float2 v;
        v.x = (j0     < H_) ? Whh[(size_t)ii * H_ + j0]     : 0.f;
        v.y = (j0 + 1 < H_) ? Whh[(size_t)ii * H_ + j0 + 1] : 0.f;
        whh2_s[idx] = v;
    }

    // zero x pads (pads never rewritten; staging covers floats < 202) + h
    for (int q = tid; q < 4 * XROW_; q += 256) (&x_buf[0][0])[q] = 0.f;
    for (int q = tid; q < 2 * HP_; q += 256) (&h_buf[0][0])[q] = 0.f;
    __syncthreads();

    // plain-stage rows 0,1
    {
        const int p0 = dir ? (S_ - 1) : 0;
        const int p1 = dir ? (S_ - 2) : 1;
        const float* r0 = x + ((size_t)p0 * B_ + b) * F_;
        const float* r1 = x + ((size_t)p1 * B_ + b) * F_;
        if (tid < F_) { x_buf[0][tid] = r0[tid]; x_buf[1][tid] = r1[tid]; }
    }
    __syncthreads();

    // wave-3 staging lanes: two float2 elements per lane (e0 always, e1 if <101)
    const int sl = tid - 192;
    const int e0 = sl;          // < 64  -> always < 101
    const int e1 = sl + 64;     // valid iff sl < 37
    float2 sA0 = {0.f, 0.f}, sA1 = {0.f, 0.f};   // row t+2 on even iters
    float2 sB0 = {0.f, 0.f}, sB1 = {0.f, 0.f};   // row t+2 on odd iters
    if (tid >= 192) {
        const int pa = dir ? (S_ - 3) : 2;       // row 2
        const int pb = dir ? (S_ - 4) : 3;       // row 3
        const float* ra = x + ((size_t)pa * B_ + b) * F_;
        const float* rb = x + ((size_t)pb * B_ + b) * F_;
        sA0 = *(const float2*)(ra + e0 * 2);
        if (e1 < 101) sA1 = *(const float2*)(ra + e1 * 2);
        sB0 = *(const float2*)(rb + e0 * 2);
        if (e1 < 101) sB1 = *(const float2*)(rb + e1 * 2);
    }

    // xp for step 0 from x_buf[0] (round-1 reduction tree, bitwise identical)
    float xp_cur = 0.f, xp_nxt = 0.f;
    if (tid < 200) {
        float a0 = 0.f, a1 = 0.f, a2 = 0.f, a3 = 0.f;
        const float* xb = &x_buf[0][hf * 104];
        #pragma unroll
        for (int q = 0; q < 26; ++q) {
            const float4 xv = *(const float4*)(xb + q * 4);
            a0 = fmaf(wih[q*4+0], xv.x, a0);
            a1 = fmaf(wih[q*4+1], xv.y, a1);
            a2 = fmaf(wih[q*4+2], xv.z, a2);
            a3 = fmaf(wih[q*4+3], xv.w, a3);
        }
        float acc = (a0 + a1) + (a2 + a3);
        acc += __shfl_xor(acc, 1);
        xp_cur = acc + bias;    // valid on hf==0
    }
    __syncthreads();

    auto STEP = [&](int t, float2& r0, float2& r1) {
        const int rh = t & 1;          // h_buf slot holding h[t-1]
        const int wh = rh ^ 1;         // slot for h[t]
        const int rx = (t + 1) & 3;    // x_buf slot holding x[t+1]

        // (1) wave 3: commit row t+2 (loaded 2 iters ago), issue loads row t+4
        if (tid >= 192) {
            if (t + 2 < S_) {
                const int ws = (t + 2) & 3;      // != rx -> no reader conflict
                *(float2*)&x_buf[ws][e0 * 2] = r0;
                if (e1 < 101) *(float2*)&x_buf[ws][e1 * 2] = r1;
            }
            if (t + 4 < S_) {
                const int p = dir ? (S_ - 5 - t) : (t + 4);
                const float* rr = x + ((size_t)p * B_ + b) * F_;
                r0 = *(const float2*)(rr + e0 * 2);
                if (e1 < 101) r1 = *(const float2*)(rr + e1 * 2);
            }
        }

        // (2) recurrence: rsum = Whh . h[t-1] + xp[t]  (round-1 tree order)
        float rsum = 0.f;
        if (tid < 200) {
            float a0 = 0.f, a1 = 0.f, a2 = 0.f, a3 = 0.f;
            const float*  hb = &h_buf[rh][hf * 56];
            const float2* wp = &whh2_s[(size_t)(hf * 28) * H_ + i];
            #pragma unroll
            for (int q = 0; q < 14; ++q) {
                const float4 hv  = *(const float4*)(hb + q * 4);
                const float2 w01 = wp[(2 * q)     * H_];
                const float2 w23 = wp[(2 * q + 1) * H_];
                a0 = fmaf(w01.x, hv.x, a0);
                a1 = fmaf(w01.y, hv.y, a1);
                a2 = fmaf(w23.x, hv.z, a2);
                a3 = fmaf(w23.y, hv.w, a3);
            }
            float acc = (a0 + a1) + (a2 + a3);
            acc += __shfl_xor(acc, 1);
            rsum = acc + xp_cur;
        }

        // (3) logits for h[t-1] (round-1 16-slice tree) -> atomicAdd
        if (t >= 1 && tid < 152) {
            float a0 = 0.f, a1 = 0.f, a2 = 0.f, a3 = 0.f;
            const float* hb2 = &h_buf[rh][ls * 16];
            #pragma unroll
            for (int q = 0; q < 4; ++q) {
                const float4 hv = *(const float4*)(hb2 + q * 4);
                a0 = fmaf(wlog[q*4+0], hv.x, a0);
                a1 = fmaf(wlog[q*4+1], hv.y, a1);
                a2 = fmaf(wlog[q*4+2], hv.z, a2);
                a3 = fmaf(wlog[q*4+3], hv.w, a3);
            }
            float acc = (a0 + a1) + (a2 + a3);
            acc += __shfl_xor(acc, 1);
            acc += __shfl_xor(acc, 2);
            acc += __shfl_xor(acc, 4);
            if (ls == 0) {
                const int pl = dir ? (S_ - t) : (t - 1);
                atomicAdd(&Lbuf[((size_t)pl * B_ + b) * K_ + lk], acc);
            }
        }

        // (4) write h[t]
        if (tid < 200 && hf == 0) h_buf[wh][i] = tanhf(rsum);

        // (5) proj for step t+1 (independent of h)
        if (t + 1 < S_ && tid < 200) {
            float a0 = 0.f, a1 = 0.f, a2 = 0.f, a3 = 0.f;
            const float* xb = &x_buf[rx][hf * 104];
            #pragma unroll
            for (int q = 0; q < 26; ++q) {
                const float4 xv = *(const float4*)(xb + q * 4);
                a0 = fmaf(wih[q*4+0], xv.x, a0);
                a1 = fmaf(wih[q*4+1], xv.y, a1);
                a2 = fmaf(wih[q*4+2], xv.z, a2);
                a3 = fmaf(wih[q*4+3], xv.w, a3);
            }
            float acc = (a0 + a1) + (a2 + a3);
            acc += __shfl_xor(acc, 1);
            xp_nxt = acc + bias;
        }
        xp_cur = xp_nxt;

        // (6) hermetic barrier: no memory op crosses in either direction;
        //     vmem (staging loads / logit atomics) stays in flight.
        __asm__ volatile("s_waitcnt lgkmcnt(0)" ::: "memory");
        __builtin_amdgcn_s_barrier();
        __asm__ volatile("" ::: "memory");
    };

    for (int t2 = 0; t2 < S_; t2 += 2) {   // unroll-by-2: static reg-set rotation
        STEP(t2,     sA0, sA1);
        STEP(t2 + 1, sB0, sB1);
    }

    // epilogue: logits for h[S-1] (written at STEP(1023) into slot 0)
    if (tid < 152) {
        float a0 = 0.f, a1 = 0.f, a2 = 0.f, a3 = 0.f;
        const float* hb2 = &h_buf[0][ls * 16];
        #pragma unroll
        for (int q = 0; q < 4; ++q) {
            const float4 hv = *(const float4*)(hb2 + q * 4);
            a0 = fmaf(wlog[q*4+0], hv.x, a0);
            a1 = fmaf(wlog[q*4+1], hv.y, a1);
            a2 = fmaf(wlog[q*4+2], hv.z, a2);
            a3 = fmaf(wlog[q*4+3], hv.w, a3);
        }
        float acc = (a0 + a1) + (a2 + a3);
        acc += __shfl_xor(acc, 1);
        acc += __shfl_xor(acc, 2);
        acc += __shfl_xor(acc, 4);
        if (ls == 0) {
            const int pl = dir ? 0 : (S_ - 1);
            atomicAdd(&Lbuf[((size_t)pl * B_ + b) * K_ + lk], acc);
        }
    }
}

// ---------------------------------------------------------------------------
// Kernel 2: round-1 Viterbi verbatim (known-passing, absmax 0.0).
// ---------------------------------------------------------------------------
__global__ __launch_bounds__(256) void viterbi_kernel(
    const float* __restrict__ Lbuf,
    const float* __restrict__ b_out,
    const float* __restrict__ start_t,
    const float* __restrict__ end_t,
    const float* __restrict__ trans,
    float* __restrict__ out)
{
    const int w    = threadIdx.x >> 6;
    const int lane = threadIdx.x & 63;
    const int n    = blockIdx.x * 4 + w;

    __shared__ float         score_s[4][20];
    __shared__ unsigned char hist_s[4][B_][20];
    __shared__ unsigned char tags_s[4][B_];

    const int kk = (lane < K_) ? lane : 0;
    float tcol[K_];
    #pragma unroll
    for (int j = 0; j < K_; ++j) tcol[j] = trans[j * K_ + kk];
    const float bko = b_out[kk];
    const float stk = start_t[kk];
    const float enk = end_t[kk];

    const float* Lrow = Lbuf + (size_t)n * B_ * K_;

    // t = 0: score = start + em[0]
    {
        float lg = -1e30f;
        if (lane < K_) lg = Lrow[kk] + bko;
        float m = lg;
        #pragma unroll
        for (int d = 16; d >= 1; d >>= 1) m = fmaxf(m, __shfl_xor(m, d, 32));
        float pp = (lane < K_) ? expf(lg - m) : 0.f;
        float ssum = pp;
        #pragma unroll
        for (int d = 16; d >= 1; d >>= 1) ssum += __shfl_xor(ssum, d, 32);
        if (lane < K_) score_s[w][lane] = stk + pp / ssum;
    }

    for (int t = 1; t < B_; ++t) {
        float lg = -1e30f;
        if (lane < K_) lg = Lrow[t * K_ + kk] + bko;
        float m = lg;
        #pragma unroll
        for (int d = 16; d >= 1; d >>= 1) m = fmaxf(m, __shfl_xor(m, d, 32));
        float pp = (lane < K_) ? expf(lg - m) : 0.f;
        float ssum = pp;
        #pragma unroll
        for (int d = 16; d >= 1; d >>= 1) ssum += __shfl_xor(ssum, d, 32);
        const float e = pp / ssum;

        float best = -1e30f; int am = 0;
        #pragma unroll
        for (int j = 0; j < K_; ++j) {
            const float v = (score_s[w][j] + tcol[j]) + e;   // ref add order
            if (v > best) { best = v; am = j; }
        }
        if (lane < K_) {
            hist_s[w][t][lane] = (unsigned char)am;
            score_s[w][lane]   = best;   // wave-lockstep: reads precede writes
        }
    }

    if (lane < K_) score_s[w][lane] += enk;

    if (lane == 0) {
        float bestv = score_s[w][0]; int bi = 0;
        for (int j = 1; j < K_; ++j) {
            const float v = score_s[w][j];
            if (v > bestv) { bestv = v; bi = j; }
        }
        int tag = bi;
        tags_s[w][B_ - 1] = (unsigned char)tag;
        for (int t = B_ - 2; t >= 0; --t) {
            tag = hist_s[w][t + 1][tag];
            tags_s[w][t] = (unsigned char)tag;
        }
    }
    out[(size_t)n * B_ + lane]      = (float)tags_s[w][lane];
    out[(size_t)n * B_ + 64 + lane] = (float)tags_s[w][64 + lane];
}

extern "C" void kernel_launch(void* const* d_in, const int* in_sizes, int n_in,
                              void* d_out, int out_size, void* d_ws, size_t ws_size,
                              hipStream_t stream)
{
    const float* x       = (const float*)d_in[0];
    const float* Wih_f   = (const float*)d_in[1];
    const float* Whh_f   = (const float*)d_in[2];
    const float* bih_f   = (const float*)d_in[3];
    const float* bhh_f   = (const float*)d_in[4];
    const float* Wih_b   = (const float*)d_in[5];
    const float* Whh_b   = (const float*)d_in[6];
    const float* bih_b   = (const float*)d_in[7];
    const float* bhh_b   = (const float*)d_in[8];
    const float* Wout    = (const float*)d_in[9];
    const float* b_out   = (const float*)d_in[10];
    const float* start_t = (const float*)d_in[11];
    const float* end_t   = (const float*)d_in[12];
    const float* trans   = (const float*)d_in[13];

    float* Lbuf = (float*)d_ws;           // (S,B,K) fp32 = ~9.96 MB (round-1-proven fit)
    float* out  = (float*)d_out;          // (S,B) fp32 tags

    hipMemsetAsync(Lbuf, 0, (size_t)S_ * B_ * K_ * sizeof(float), stream);

    rnn_chain_kernel<<<dim3(256), dim3(256), 0, stream>>>(
        x, Wih_f, Whh_f, bih_f, bhh_f, Wih_b, Whh_b, bih_b, bhh_b, Wout, Lbuf);

    viterbi_kernel<<<dim3(256), dim3(256), 0, stream>>>(
        Lbuf, b_out, start_t, end_t, trans, out);
}

// Round 7
// 1323.205 us; speedup vs baseline: 1.2667x; 1.2667x over previous
//
#include <hip/hip_runtime.h>
#include <math.h>

#define S_ 1024
#define B_ 128
#define F_ 202
#define H_ 100
#define K_ 19
#define XROW_ 208   // x row padded, 16B-aligned
#define HP_ 128     // h padded: recur reads 2x56, logit reads 8x16

// ---------------------------------------------------------------------------
// Kernel 1: one 512-thread workgroup per (direction, batch) chain, 8 waves
// (2 per SIMD). 4-way thread split per dot product so per-thread weights are
// 13+7(+4) float4s -> small vector allocas the compiler provably promotes to
// VGPRs (rounds 1/4: 104/56-float arrays -> scratch demotion, VGPR_Count
// 112-116 << footprint, ~3400 cy/step reload latency at 1 wave/SIMD).
//
// Bitwise-identical arithmetic to the round-1 passing kernel:
//   thread q4=(hf,jp) owns round-1 accumulator chains a_{2jp}, a_{2jp+1} of
//   half hf (same fmaf order); shfl_xor(1) = (a0+a1)+(a2+a3) per half;
//   shfl_xor(2) = half0+half1; then +xp / +bias as in round 1.
// Staging pipeline, hermetic barrier, logit tree, atomics: round-4 verbatim.
// ---------------------------------------------------------------------------
__global__ __launch_bounds__(512, 2) void rnn_chain_kernel(
    const float* __restrict__ x,
    const float* __restrict__ Wih_f, const float* __restrict__ Whh_f,
    const float* __restrict__ bih_f, const float* __restrict__ bhh_f,
    const float* __restrict__ Wih_b, const float* __restrict__ Whh_b,
    const float* __restrict__ bih_b, const float* __restrict__ bhh_b,
    const float* __restrict__ Wout,
    float* __restrict__ Lbuf)
{
    const int tid = threadIdx.x;
    const int dir = blockIdx.x >> 7;   // 0 = forward, 1 = backward
    const int b   = blockIdx.x & 127;

    const float* Wih = dir ? Wih_b : Wih_f;
    const float* Whh = dir ? Whh_b : Whh_f;
    const float* bih = dir ? bih_b : bih_f;
    const float* bhh = dir ? bhh_b : bhh_f;

    __shared__ __align__(16) float x_buf[4][XROW_];
    __shared__ __align__(16) float h_buf[2][HP_];

    // proj/recur roles: tid < 400
    const int i  = tid >> 2;         // output index 0..99
    const int q4 = tid & 3;
    const int jp = q4 & 1;           // accumulator-pair (a_{2jp}, a_{2jp+1})
    const int hf = q4 >> 1;          // which half of the dot
    // logit role: tid >= 360 (8-group aligned; 152 threads = 19 tags x 8)
    const int lt = tid - 360;
    const int lk = lt >> 3;          // tag k 0..18
    const int ls = lt & 7;

    // weights as SMALL float4 allocas (SROA-promotable), const indices only
    float4 wih4[13];   // chains q=0..25: f = hf*104 + 4q + 2jp + {0,1}
    float4 whh4[7];    // chains q=0..13: j = hf*56  + 4q + 2jp + {0,1}
    float4 wlog4[4];   // logit slice (round-1 layout)
    float bias = 0.f;

    if (tid < 400) {
        const int fb = hf * 104 + 2 * jp;
        #pragma unroll
        for (int q = 0; q < 26; ++q) {
            const int f = fb + 4 * q;           // even; loads [f, f+1]
            float vx = 0.f, vy = 0.f;
            if (f <= 200) {
                const float2 wv = *(const float2*)(&Wih[(size_t)i * F_ + f]);
                vx = wv.x; vy = wv.y;
            }
            if (q & 1) { wih4[q >> 1].z = vx; wih4[q >> 1].w = vy; }
            else       { wih4[q >> 1].x = vx; wih4[q >> 1].y = vy; }
        }
        const int jb = hf * 56 + 2 * jp;
        #pragma unroll
        for (int q = 0; q < 14; ++q) {
            const int j = jb + 4 * q;           // even; loads [j, j+1]
            float vx = 0.f, vy = 0.f;
            if (j <= 98) {
                const float2 wv = *(const float2*)(&Whh[(size_t)i * H_ + j]);
                vx = wv.x; vy = wv.y;
            }
            if (q & 1) { whh4[q >> 1].z = vx; whh4[q >> 1].w = vy; }
            else       { whh4[q >> 1].x = vx; whh4[q >> 1].y = vy; }
        }
        if (q4 == 0) bias = bih[i] + bhh[i];
    } else {
        #pragma unroll
        for (int q = 0; q < 13; ++q) wih4[q] = {0.f, 0.f, 0.f, 0.f};
        #pragma unroll
        for (int q = 0; q < 7;  ++q) whh4[q] = {0.f, 0.f, 0.f, 0.f};
    }
    if (tid >= 360) {
        #pragma unroll
        for (int q = 0; q < 4; ++q) {
            float4 v;
            const int j0 = ls * 16 + q * 4;
            v.x = (j0 + 0 < H_) ? Wout[(size_t)lk * (2 * H_) + dir * H_ + j0 + 0] : 0.f;
            v.y = (j0 + 1 < H_) ? Wout[(size_t)lk * (2 * H_) + dir * H_ + j0 + 1] : 0.f;
            v.z = (j0 + 2 < H_) ? Wout[(size_t)lk * (2 * H_) + dir * H_ + j0 + 2] : 0.f;
            v.w = (j0 + 3 < H_) ? Wout[(size_t)lk * (2 * H_) + dir * H_ + j0 + 3] : 0.f;
            wlog4[q] = v;
        }
    } else {
        #pragma unroll
        for (int q = 0; q < 4; ++q) wlog4[q] = {0.f, 0.f, 0.f, 0.f};
    }

    // zero x pads (never rewritten; staging covers floats < 202) + h init
    for (int q = tid; q < 4 * XROW_; q += 512) (&x_buf[0][0])[q] = 0.f;
    if (tid < 2 * HP_) (&h_buf[0][0])[tid] = 0.f;
    __syncthreads();

    // plain-stage rows 0,1
    {
        const int p0 = dir ? (S_ - 1) : 0;
        const int p1 = dir ? (S_ - 2) : 1;
        const float* r0 = x + ((size_t)p0 * B_ + b) * F_;
        const float* r1 = x + ((size_t)p1 * B_ + b) * F_;
        if (tid < F_) { x_buf[0][tid] = r0[tid]; x_buf[1][tid] = r1[tid]; }
    }
    __syncthreads();

    // wave-7 staging lanes: two float2 elements per lane (e0 always, e1 if <101)
    const int sl = tid - 448;
    const int e0 = sl;          // float2 index 0..63  (floats 0..127)
    const int e1 = sl + 64;     // float2 index 64..100 iff sl < 37 (floats 128..201)
    float2 sA0 = {0.f, 0.f}, sA1 = {0.f, 0.f};   // holds x row t+2 on even iters
    float2 sB0 = {0.f, 0.f}, sB1 = {0.f, 0.f};   // holds x row t+2 on odd iters
    if (tid >= 448) {
        const int pa = dir ? (S_ - 3) : 2;       // row 2
        const int pb = dir ? (S_ - 4) : 3;       // row 3
        const float* ra = x + ((size_t)pa * B_ + b) * F_;
        const float* rb = x + ((size_t)pb * B_ + b) * F_;
        sA0 = *(const float2*)(ra + e0 * 2);
        if (e1 < 101) sA1 = *(const float2*)(ra + e1 * 2);
        sB0 = *(const float2*)(rb + e0 * 2);
        if (e1 < 101) sB1 = *(const float2*)(rb + e1 * 2);
    }

    // xp for step 0 from x_buf[0] (bitwise round-1 tree via 4-thread split)
    float xp_cur = 0.f, xp_nxt = 0.f;
    if (tid < 400) {
        float c0 = 0.f, c1 = 0.f;
        const float* xb = &x_buf[0][hf * 104 + 2 * jp];
        #pragma unroll
        for (int q = 0; q < 26; ++q) {
            const float2 xv = *(const float2*)(xb + 4 * q);
            const float4 wq = wih4[q >> 1];
            c0 = fmaf((q & 1) ? wq.z : wq.x, xv.x, c0);   // chain a_{2jp}
            c1 = fmaf((q & 1) ? wq.w : wq.y, xv.y, c1);   // chain a_{2jp+1}
        }
        float acc = c0 + c1;                    // a_{2jp} + a_{2jp+1}
        acc += __shfl_xor(acc, 1);              // (a0+a1) + (a2+a3)   [per half]
        acc += __shfl_xor(acc, 2);              // half0 + half1
        xp_cur = acc + bias;                    // valid on q4==0
    }
    __syncthreads();

    auto STEP = [&](int t, float2& r0, float2& r1) {
        const int rh = t & 1;          // h_buf slot holding h[t-1]
        const int wh = rh ^ 1;         // slot for h[t]
        const int rx = (t + 1) & 3;    // x_buf slot holding x[t+1]

        // (1) wave 7: commit row t+2 (loaded 2 iters ago), issue loads row t+4
        if (tid >= 448) {
            if (t + 2 < S_) {
                const int ws = (t + 2) & 3;      // != rx -> no reader conflict
                *(float2*)&x_buf[ws][e0 * 2] = r0;
                if (e1 < 101) *(float2*)&x_buf[ws][e1 * 2] = r1;
            }
            if (t + 4 < S_) {
                const int p = dir ? (S_ - 5 - t) : (t + 4);
                const float* rr = x + ((size_t)p * B_ + b) * F_;
                r0 = *(const float2*)(rr + e0 * 2);
                if (e1 < 101) r1 = *(const float2*)(rr + e1 * 2);
            }
        }

        // (2) recurrence: rsum = Whh . h[t-1] + xp[t]  (bitwise round-1 tree)
        if (tid < 400) {
            float c0 = 0.f, c1 = 0.f;
            const float* hb = &h_buf[rh][hf * 56 + 2 * jp];
            #pragma unroll
            for (int q = 0; q < 14; ++q) {
                const float2 hv = *(const float2*)(hb + 4 * q);
                const float4 wq = whh4[q >> 1];
                c0 = fmaf((q & 1) ? wq.z : wq.x, hv.x, c0);
                c1 = fmaf((q & 1) ? wq.w : wq.y, hv.y, c1);
            }
            float acc = c0 + c1;
            acc += __shfl_xor(acc, 1);
            acc += __shfl_xor(acc, 2);
            if (q4 == 0) {
                const float v = acc + xp_cur;
                h_buf[wh][i] = tanhf(v);
            }
        }

        // (3) logits for h[t-1] (round-1 16-slice tree) -> atomicAdd
        if (t >= 1 && tid >= 360) {
            float a0 = 0.f, a1 = 0.f, a2 = 0.f, a3 = 0.f;
            const float* hb2 = &h_buf[rh][ls * 16];
            #pragma unroll
            for (int q = 0; q < 4; ++q) {
                const float4 hv = *(const float4*)(hb2 + q * 4);
                a0 = fmaf(wlog4[q].x, hv.x, a0);
                a1 = fmaf(wlog4[q].y, hv.y, a1);
                a2 = fmaf(wlog4[q].z, hv.z, a2);
                a3 = fmaf(wlog4[q].w, hv.w, a3);
            }
            float acc = (a0 + a1) + (a2 + a3);
            acc += __shfl_xor(acc, 1);
            acc += __shfl_xor(acc, 2);
            acc += __shfl_xor(acc, 4);
            if (ls == 0) {
                const int pl = dir ? (S_ - t) : (t - 1);
                atomicAdd(&Lbuf[((size_t)pl * B_ + b) * K_ + lk], acc);
            }
        }

        // (4) proj for step t+1 (independent of h)
        if (t + 1 < S_ && tid < 400) {
            float c0 = 0.f, c1 = 0.f;
            const float* xb = &x_buf[rx][hf * 104 + 2 * jp];
            #pragma unroll
            for (int q = 0; q < 26; ++q) {
                const float2 xv = *(const float2*)(xb + 4 * q);
                const float4 wq = wih4[q >> 1];
                c0 = fmaf((q & 1) ? wq.z : wq.x, xv.x, c0);
                c1 = fmaf((q & 1) ? wq.w : wq.y, xv.y, c1);
            }
            float acc = c0 + c1;
            acc += __shfl_xor(acc, 1);
            acc += __shfl_xor(acc, 2);
            xp_nxt = acc + bias;
        }
        xp_cur = xp_nxt;

        // (5) hermetic barrier: no memory op crosses in either direction;
        //     vmem (staging loads / logit atomics) stays in flight.
        __asm__ volatile("s_waitcnt lgkmcnt(0)" ::: "memory");
        __builtin_amdgcn_s_barrier();
        __asm__ volatile("" ::: "memory");
    };

    for (int t2 = 0; t2 < S_; t2 += 2) {   // unroll-by-2: static reg-set rotation
        STEP(t2,     sA0, sA1);
        STEP(t2 + 1, sB0, sB1);
    }

    // epilogue: logits for h[S-1] (written at STEP(1023) into slot 0)
    if (tid >= 360) {
        float a0 = 0.f, a1 = 0.f, a2 = 0.f, a3 = 0.f;
        const float* hb2 = &h_buf[0][ls * 16];
        #pragma unroll
        for (int q = 0; q < 4; ++q) {
            const float4 hv = *(const float4*)(hb2 + q * 4);
            a0 = fmaf(wlog4[q].x, hv.x, a0);
            a1 = fmaf(wlog4[q].y, hv.y, a1);
            a2 = fmaf(wlog4[q].z, hv.z, a2);
            a3 = fmaf(wlog4[q].w, hv.w, a3);
        }
        float acc = (a0 + a1) + (a2 + a3);
        acc += __shfl_xor(acc, 1);
        acc += __shfl_xor(acc, 2);
        acc += __shfl_xor(acc, 4);
        if (ls == 0) {
            const int pl = dir ? 0 : (S_ - 1);
            atomicAdd(&Lbuf[((size_t)pl * B_ + b) * K_ + lk], acc);
        }
    }
}

// ---------------------------------------------------------------------------
// Kernel 2: round-1 Viterbi verbatim (known-passing, absmax 0.0).
// ---------------------------------------------------------------------------
__global__ __launch_bounds__(256) void viterbi_kernel(
    const float* __restrict__ Lbuf,
    const float* __restrict__ b_out,
    const float* __restrict__ start_t,
    const float* __restrict__ end_t,
    const float* __restrict__ trans,
    float* __restrict__ out)
{
    const int w    = threadIdx.x >> 6;
    const int lane = threadIdx.x & 63;
    const int n    = blockIdx.x * 4 + w;

    __shared__ float         score_s[4][20];
    __shared__ unsigned char hist_s[4][B_][20];
    __shared__ unsigned char tags_s[4][B_];

    const int kk = (lane < K_) ? lane : 0;
    float tcol[K_];
    #pragma unroll
    for (int j = 0; j < K_; ++j) tcol[j] = trans[j * K_ + kk];
    const float bko = b_out[kk];
    const float stk = start_t[kk];
    const float enk = end_t[kk];

    const float* Lrow = Lbuf + (size_t)n * B_ * K_;

    // t = 0: score = start + em[0]
    {
        float lg = -1e30f;
        if (lane < K_) lg = Lrow[kk] + bko;
        float m = lg;
        #pragma unroll
        for (int d = 16; d >= 1; d >>= 1) m = fmaxf(m, __shfl_xor(m, d, 32));
        float pp = (lane < K_) ? expf(lg - m) : 0.f;
        float ssum = pp;
        #pragma unroll
        for (int d = 16; d >= 1; d >>= 1) ssum += __shfl_xor(ssum, d, 32);
        if (lane < K_) score_s[w][lane] = stk + pp / ssum;
    }

    for (int t = 1; t < B_; ++t) {
        float lg = -1e30f;
        if (lane < K_) lg = Lrow[t * K_ + kk] + bko;
        float m = lg;
        #pragma unroll
        for (int d = 16; d >= 1; d >>= 1) m = fmaxf(m, __shfl_xor(m, d, 32));
        float pp = (lane < K_) ? expf(lg - m) : 0.f;
        float ssum = pp;
        #pragma unroll
        for (int d = 16; d >= 1; d >>= 1) ssum += __shfl_xor(ssum, d, 32);
        const float e = pp / ssum;

        float best = -1e30f; int am = 0;
        #pragma unroll
        for (int j = 0; j < K_; ++j) {
            const float v = (score_s[w][j] + tcol[j]) + e;   // ref add order
            if (v > best) { best = v; am = j; }
        }
        if (lane < K_) {
            hist_s[w][t][lane] = (unsigned char)am;
            score_s[w][lane]   = best;   // wave-lockstep: reads precede writes
        }
    }

    if (lane < K_) score_s[w][lane] += enk;

    if (lane == 0) {
        float bestv = score_s[w][0]; int bi = 0;
        for (int j = 1; j < K_; ++j) {
            const float v = score_s[w][j];
            if (v > bestv) { bestv = v; bi = j; }
        }
        int tag = bi;
        tags_s[w][B_ - 1] = (unsigned char)tag;
        for (int t = B_ - 2; t >= 0; --t) {
            tag = hist_s[w][t + 1][tag];
            tags_s[w][t] = (unsigned char)tag;
        }
    }
    out[(size_t)n * B_ + lane]      = (float)tags_s[w][lane];
    out[(size_t)n * B_ + 64 + lane] = (float)tags_s[w][64 + lane];
}

extern "C" void kernel_launch(void* const* d_in, const int* in_sizes, int n_in,
                              void* d_out, int out_size, void* d_ws, size_t ws_size,
                              hipStream_t stream)
{
    const float* x       = (const float*)d_in[0];
    const float* Wih_f   = (const float*)d_in[1];
    const float* Whh_f   = (const float*)d_in[2];
    const float* bih_f   = (const float*)d_in[3];
    const float* bhh_f   = (const float*)d_in[4];
    const float* Wih_b   = (const float*)d_in[5];
    const float* Whh_b   = (const float*)d_in[6];
    const float* bih_b   = (const float*)d_in[7];
    const float* bhh_b   = (const float*)d_in[8];
    const float* Wout    = (const float*)d_in[9];
    const float* b_out   = (const float*)d_in[10];
    const float* start_t = (const float*)d_in[11];
    const float* end_t   = (const float*)d_in[12];
    const float* trans   = (const float*)d_in[13];

    float* Lbuf = (float*)d_ws;           // (S,B,K) fp32 = ~9.96 MB (proven fit)
    float* out  = (float*)d_out;          // (S,B) fp32 tags

    hipMemsetAsync(Lbuf, 0, (size_t)S_ * B_ * K_ * sizeof(float), stream);

    rnn_chain_kernel<<<dim3(256), dim3(512), 0, stream>>>(
        x, Wih_f, Whh_f, bih_f, bhh_f, Wih_b, Whh_b, bih_b, bhh_b, Wout, Lbuf);

    viterbi_kernel<<<dim3(256), dim3(256), 0, stream>>>(
        Lbuf, b_out, start_t, end_t, trans, out);
}